// Round 6
// baseline (278.341 us; speedup 1.0000x reference)
//
#include <hip/hip_runtime.h>

// Problem constants (fixed by the reference setup)
constexpr int NV   = 50000;    // num vertices
constexpr int NE   = 20000;    // num hyperedges
constexpr int NNZI = 320000;   // num incidences
constexpr int KD   = 256;      // input feature dim
constexpr int DD   = 256;      // projected feature dim (heads*out)
constexpr int ECAP = 64;       // per-edge incidence capacity (Poisson(16): P(>64) ~ 1e-20)
constexpr int VCAP = 32;       // per-vertex incidence capacity (Poisson(6.4): P(>32) ~ 1e-15)

constexpr size_t alignup256(size_t x) { return (x + 255) & ~(size_t)255; }

constexpr size_t XP_BYTES    = (size_t)NV * DD * sizeof(float);   // 51.2 MB
constexpr size_t XE_BYTES    = (size_t)NE * DD * sizeof(float);   // 20.5 MB
constexpr size_t DEGV_BYTES  = alignup256((size_t)NV * sizeof(int));
constexpr size_t DEGE_BYTES  = alignup256((size_t)NE * sizeof(int));
constexpr size_t VLIST_BYTES = (size_t)NV * VCAP * sizeof(int);   // 6.4 MB
constexpr size_t ELIST_BYTES = (size_t)NE * ECAP * sizeof(int);   // 5.1 MB
// packed W fragments: 8 ksteps x 16 ntiles x 64 lanes x 8 bf16 = 128 KB each
constexpr size_t BPACK_ELEMS = 8ull * 16 * 64 * 8;
constexpr size_t BPACK_BYTES = BPACK_ELEMS * sizeof(unsigned short);

constexpr size_t XP_OFF    = 0;
constexpr size_t XE_OFF    = XP_OFF + XP_BYTES;
constexpr size_t DEGV_OFF  = XE_OFF + XE_BYTES;
constexpr size_t DEGE_OFF  = DEGV_OFF + DEGV_BYTES;
constexpr size_t VLIST_OFF = DEGE_OFF + DEGE_BYTES;
constexpr size_t ELIST_OFF = VLIST_OFF + VLIST_BYTES;
constexpr size_t BH_OFF    = ELIST_OFF + ELIST_BYTES;
constexpr size_t BL_OFF    = BH_OFF + BPACK_BYTES;
// total ~84 MB of ws

typedef float  floatx4 __attribute__((ext_vector_type(4)));
typedef short  shortx8 __attribute__((ext_vector_type(8)));

// RTNE float -> bf16 bits (inputs are well-behaved normals; NaN path not needed)
static __device__ __forceinline__ unsigned short f2bf(float x) {
    unsigned int u = __float_as_uint(x);
    u = u + 0x7fffu + ((u >> 16) & 1u);
    return (unsigned short)(u >> 16);
}
static __device__ __forceinline__ float bf2f(unsigned short h) {
    return __uint_as_float(((unsigned int)h) << 16);
}

// ---------------------------------------------------------------------------
// Pack W (fp32 [K][D] row-major) into MFMA B-fragment layout, split hi/lo bf16.
// Fragment (k0, nt, lane) holds 8 bf16: W[k0*32 + (lane>>4)*8 + j][nt*16 + (lane&15)]
// ---------------------------------------------------------------------------
__global__ __launch_bounds__(256) void pack_w(
        const float* __restrict__ W,
        unsigned short* __restrict__ Bh, unsigned short* __restrict__ Bl) {
    const int idx  = blockIdx.x * 256 + threadIdx.x;  // 0..8191
    const int k0   = idx >> 10;          // 0..7
    const int nt   = (idx >> 6) & 15;    // 0..15
    const int lane = idx & 63;
    const int krow = k0 * 32 + ((lane >> 4) << 3);
    const int ncol = nt * 16 + (lane & 15);
#pragma unroll
    for (int j = 0; j < 8; ++j) {
        const float w = W[(size_t)(krow + j) * DD + ncol];
        const unsigned short h = f2bf(w);
        Bh[(size_t)idx * 8 + j] = h;
        Bl[(size_t)idx * 8 + j] = f2bf(w - bf2f(h));
    }
}

// ---------------------------------------------------------------------------
// GEMM via split-bf16 MFMA, TLP-first structure (round-5 post-mortem):
// rounds 4+5 showed identical 68-70us for L2-direct vs LDS-staged B => B-path
// was never the bottleneck; the kernel was latency-serialized at 1.5 waves/SIMD
// with acc=128 VGPR. This version splits N across the grid:
//   block = 256 thr = 2x2 waves, tile 64 rows x 128 cols
//   wave  = 32 rows x 64 cols, acc[2][4] = 32 VGPR, no LDS
//   grid  = (782, 2) = 6256 waves (~4-6 resident/SIMD, VGPR-bound only)
// B fragments come straight from the 256 KB L2-resident packed buffers.
// hi*hi + hi*lo + lo*hi (lo*lo dropped) -> ~1e-4 abs err on O(1) values.
// ---------------------------------------------------------------------------
__global__ __launch_bounds__(256) void gemm_mfma(
        const float* __restrict__ X,
        const unsigned short* __restrict__ Bh, const unsigned short* __restrict__ Bl,
        float* __restrict__ Xp) {
    const int lane = threadIdx.x & 63;
    const int wv   = threadIdx.x >> 6;                 // 0..3
    const int row_base = blockIdx.x * 64 + (wv >> 1) * 32;
    const int ntg0     = blockIdx.y * 8 + (wv & 1) * 4;  // global n-tile base (0,4,8,12)

    floatx4 acc[2][4];
#pragma unroll
    for (int mt = 0; mt < 2; ++mt)
#pragma unroll
        for (int nt = 0; nt < 4; ++nt) acc[mt][nt] = (floatx4)0.f;

    const int lrow   = lane & 15;          // m within tile
    const int kgroup = (lane >> 4) << 3;   // k sub-offset (0,8,16,24)

    int r0 = row_base + lrow;       if (r0 >= NV) r0 = NV - 1;  // clamp; stores guarded
    int r1 = row_base + 16 + lrow;  if (r1 >= NV) r1 = NV - 1;
    const float* pA0 = &X[(size_t)r0 * KD + kgroup];
    const float* pA1 = &X[(size_t)r1 * KD + kgroup];

    for (int k0 = 0; k0 < 8; ++k0) {
        // B fragments for this phase: 4 nt x (hi,lo), per-lane b128 from L2
        shortx8 bh[4], bl[4];
#pragma unroll
        for (int nt = 0; nt < 4; ++nt) {
            const size_t boff = ((size_t)(k0 * 16 + ntg0 + nt) * 64 + lane) * 8;
            bh[nt] = *reinterpret_cast<const shortx8*>(&Bh[boff]);
            bl[nt] = *reinterpret_cast<const shortx8*>(&Bl[boff]);
        }
        // A: two rows' worth of 8 fp32, split to hi/lo bf16 in-register
        float xv[2][8];
        *reinterpret_cast<float4*>(&xv[0][0]) = *reinterpret_cast<const float4*>(pA0 + k0 * 32);
        *reinterpret_cast<float4*>(&xv[0][4]) = *reinterpret_cast<const float4*>(pA0 + k0 * 32 + 4);
        *reinterpret_cast<float4*>(&xv[1][0]) = *reinterpret_cast<const float4*>(pA1 + k0 * 32);
        *reinterpret_cast<float4*>(&xv[1][4]) = *reinterpret_cast<const float4*>(pA1 + k0 * 32 + 4);
        shortx8 ah[2], al[2];
#pragma unroll
        for (int mt = 0; mt < 2; ++mt)
#pragma unroll
            for (int j = 0; j < 8; ++j) {
                const unsigned short h = f2bf(xv[mt][j]);
                ah[mt][j] = (short)h;
                al[mt][j] = (short)f2bf(xv[mt][j] - bf2f(h));
            }
#pragma unroll
        for (int nt = 0; nt < 4; ++nt)
#pragma unroll
            for (int mt = 0; mt < 2; ++mt) {
                acc[mt][nt] = __builtin_amdgcn_mfma_f32_16x16x32_bf16(ah[mt], bh[nt], acc[mt][nt], 0, 0, 0);
                acc[mt][nt] = __builtin_amdgcn_mfma_f32_16x16x32_bf16(ah[mt], bl[nt], acc[mt][nt], 0, 0, 0);
                acc[mt][nt] = __builtin_amdgcn_mfma_f32_16x16x32_bf16(al[mt], bh[nt], acc[mt][nt], 0, 0, 0);
            }
    }

    // D fragment: col = lane&15, row = (lane>>4)*4 + reg   [m89-verified]
    const int rgroup = (lane >> 4) << 2;
#pragma unroll
    for (int mt = 0; mt < 2; ++mt) {
#pragma unroll
        for (int r = 0; r < 4; ++r) {
            const int row = row_base + mt * 16 + rgroup + r;
            if (row < NV) {
#pragma unroll
                for (int nt = 0; nt < 4; ++nt)
                    Xp[(size_t)row * DD + (ntg0 + nt) * 16 + (lane & 15)] = acc[mt][nt][r];
            }
        }
    }
}

// ---------------------------------------------------------------------------
// Build capacity-padded CSR for both directions in one pass (int atomics only).
// ---------------------------------------------------------------------------
__global__ __launch_bounds__(256) void build_csr(
        const int* __restrict__ vertex, const int* __restrict__ edges,
        int* __restrict__ deg_v, int* __restrict__ deg_e,
        int* __restrict__ vlist, int* __restrict__ elist) {
    const int i = blockIdx.x * blockDim.x + threadIdx.x;
    if (i >= NNZI) return;
    const int v = vertex[i];
    const int e = edges[i];
    const int pe = atomicAdd(&deg_e[e], 1);
    if (pe < ECAP) elist[(size_t)e * ECAP + pe] = v;
    const int pv = atomicAdd(&deg_v[v], 1);
    if (pv < VCAP) vlist[(size_t)v * VCAP + pv] = e;
}

// ---------------------------------------------------------------------------
// Edge aggregation: Xe[e,:] = sum over incidences of Xp[v,:]
// One wave per edge; lane owns a float4 of the 256-dim row.
// x4 unroll: 4 independent row loads in flight per step.
// ---------------------------------------------------------------------------
__global__ __launch_bounds__(256) void edge_gather(
        const float* __restrict__ Xp, const int* __restrict__ deg_e,
        const int* __restrict__ elist, float* __restrict__ Xe) {
    const int lane = threadIdx.x & 63;
    const int wid  = (blockIdx.x * blockDim.x + threadIdx.x) >> 6;
    if (wid >= NE) return;
    int cnt = deg_e[wid];
    if (cnt > ECAP) cnt = ECAP;
    const int idxl = elist[(size_t)wid * ECAP + lane];
    const int col  = lane * 4;
    float ax = 0.f, ay = 0.f, az = 0.f, aw = 0.f;
    int j = 0;
    for (; j + 4 <= cnt; j += 4) {
        const int v0 = __shfl(idxl, j + 0);
        const int v1 = __shfl(idxl, j + 1);
        const int v2 = __shfl(idxl, j + 2);
        const int v3 = __shfl(idxl, j + 3);
        const float4 x0 = *reinterpret_cast<const float4*>(&Xp[(size_t)v0 * DD + col]);
        const float4 x1 = *reinterpret_cast<const float4*>(&Xp[(size_t)v1 * DD + col]);
        const float4 x2 = *reinterpret_cast<const float4*>(&Xp[(size_t)v2 * DD + col]);
        const float4 x3 = *reinterpret_cast<const float4*>(&Xp[(size_t)v3 * DD + col]);
        ax += x0.x + x1.x + x2.x + x3.x;
        ay += x0.y + x1.y + x2.y + x3.y;
        az += x0.z + x1.z + x2.z + x3.z;
        aw += x0.w + x1.w + x2.w + x3.w;
    }
    for (; j < cnt; ++j) {
        const int v = __shfl(idxl, j);
        const float4 x = *reinterpret_cast<const float4*>(&Xp[(size_t)v * DD + col]);
        ax += x.x; ay += x.y; az += x.z; aw += x.w;
    }
    float4 o; o.x = ax; o.y = ay; o.z = az; o.w = aw;
    *reinterpret_cast<float4*>(&Xe[(size_t)wid * DD + col]) = o;
}

// ---------------------------------------------------------------------------
// Vertex aggregation + GIN update: out[v,:] = (1+eps)*Xp[v,:] + sum Xe[e,:]
// ---------------------------------------------------------------------------
__global__ __launch_bounds__(256) void vertex_gather(
        const float* __restrict__ Xp, const float* __restrict__ Xe,
        const int* __restrict__ deg_v, const int* __restrict__ vlist,
        const float* __restrict__ eps, float* __restrict__ out) {
    const int lane = threadIdx.x & 63;
    const int wid  = (blockIdx.x * blockDim.x + threadIdx.x) >> 6;
    if (wid >= NV) return;
    int cnt = deg_v[wid];
    if (cnt > VCAP) cnt = VCAP;
    // lanes 32..63 read past this row -- harmless: never selected by __shfl (cnt <= 32)
    const int idxl = vlist[(size_t)wid * VCAP + lane];
    const int col  = lane * 4;
    const float e1 = 1.0f + eps[0];
    const float4 x = *reinterpret_cast<const float4*>(&Xp[(size_t)wid * DD + col]);
    float ax = e1 * x.x, ay = e1 * x.y, az = e1 * x.z, aw = e1 * x.w;
    int j = 0;
    for (; j + 4 <= cnt; j += 4) {
        const int e0 = __shfl(idxl, j + 0);
        const int e1i = __shfl(idxl, j + 1);
        const int e2 = __shfl(idxl, j + 2);
        const int e3 = __shfl(idxl, j + 3);
        const float4 t0 = *reinterpret_cast<const float4*>(&Xe[(size_t)e0 * DD + col]);
        const float4 t1 = *reinterpret_cast<const float4*>(&Xe[(size_t)e1i * DD + col]);
        const float4 t2 = *reinterpret_cast<const float4*>(&Xe[(size_t)e2 * DD + col]);
        const float4 t3 = *reinterpret_cast<const float4*>(&Xe[(size_t)e3 * DD + col]);
        ax += t0.x + t1.x + t2.x + t3.x;
        ay += t0.y + t1.y + t2.y + t3.y;
        az += t0.z + t1.z + t2.z + t3.z;
        aw += t0.w + t1.w + t2.w + t3.w;
    }
    for (; j < cnt; ++j) {
        const int e = __shfl(idxl, j);
        const float4 t = *reinterpret_cast<const float4*>(&Xe[(size_t)e * DD + col]);
        ax += t.x; ay += t.y; az += t.z; aw += t.w;
    }
    float4 o; o.x = ax; o.y = ay; o.z = az; o.w = aw;
    *reinterpret_cast<float4*>(&out[(size_t)wid * DD + col]) = o;
}

// ---------------------------------------------------------------------------
extern "C" void kernel_launch(void* const* d_in, const int* in_sizes, int n_in,
                              void* d_out, int out_size, void* d_ws, size_t ws_size,
                              hipStream_t stream) {
    const float* X      = (const float*)d_in[0];
    const int*   vertex = (const int*)d_in[1];
    const int*   edges  = (const int*)d_in[2];
    const float* W      = (const float*)d_in[3];
    const float* eps    = (const float*)d_in[4];
    float* out = (float*)d_out;
    char*  ws  = (char*)d_ws;

    float* Xp    = (float*)(ws + XP_OFF);
    float* Xe    = (float*)(ws + XE_OFF);
    int*   deg_v = (int*)(ws + DEGV_OFF);
    int*   deg_e = (int*)(ws + DEGE_OFF);
    int*   vlist = (int*)(ws + VLIST_OFF);
    int*   elist = (int*)(ws + ELIST_OFF);
    unsigned short* Bh = (unsigned short*)(ws + BH_OFF);
    unsigned short* Bl = (unsigned short*)(ws + BL_OFF);

    // ws is re-poisoned 0xAA before every timed call: zero the degree counters.
    hipMemsetAsync(ws + DEGV_OFF, 0, DEGV_BYTES + DEGE_BYTES, stream);

    pack_w<<<32, 256, 0, stream>>>(W, Bh, Bl);
    gemm_mfma<<<dim3((NV + 63) / 64, 2), 256, 0, stream>>>(X, Bh, Bl, Xp);
    build_csr<<<(NNZI + 255) / 256, 256, 0, stream>>>(vertex, edges, deg_v, deg_e, vlist, elist);
    edge_gather<<<(NE + 3) / 4, 256, 0, stream>>>(Xp, deg_e, elist, Xe);
    vertex_gather<<<(NV + 3) / 4, 256, 0, stream>>>(Xp, Xe, deg_v, vlist, eps, out);
}

// Round 7
// 227.423 us; speedup vs baseline: 1.2239x; 1.2239x over previous
//
#include <hip/hip_runtime.h>

// Problem constants (fixed by the reference setup)
constexpr int NV   = 50000;    // num vertices
constexpr int NE   = 20000;    // num hyperedges
constexpr int NNZI = 320000;   // num incidences
constexpr int KD   = 256;      // input feature dim
constexpr int DD   = 256;      // projected feature dim (heads*out)
constexpr int ECAP = 64;       // per-edge incidence capacity (Poisson(16): P(>64) ~ 1e-20)
constexpr int VCAP = 32;       // per-vertex incidence capacity (Poisson(6.4): P(>32) ~ 1e-15)

constexpr size_t alignup256(size_t x) { return (x + 255) & ~(size_t)255; }

// fp16 gather operands (round-6: gathers are capacity-miss bound; halve bytes)
constexpr size_t XPH_BYTES   = (size_t)NV * DD * 2;               // 25.6 MB
constexpr size_t XEH_BYTES   = (size_t)NE * DD * 2;               // 10.2 MB
constexpr size_t DEGV_BYTES  = alignup256((size_t)NV * sizeof(int));
constexpr size_t DEGE_BYTES  = alignup256((size_t)NE * sizeof(int));
constexpr size_t VLIST_BYTES = (size_t)NV * VCAP * sizeof(int);   // 6.4 MB
constexpr size_t ELIST_BYTES = (size_t)NE * ECAP * sizeof(int);   // 5.1 MB
constexpr size_t BPACK_ELEMS = 8ull * 16 * 64 * 8;
constexpr size_t BPACK_BYTES = BPACK_ELEMS * sizeof(unsigned short);

constexpr size_t XPH_OFF   = 0;
constexpr size_t XEH_OFF   = XPH_OFF + XPH_BYTES;
constexpr size_t DEGV_OFF  = XEH_OFF + XEH_BYTES;
constexpr size_t DEGE_OFF  = DEGV_OFF + DEGV_BYTES;
constexpr size_t VLIST_OFF = DEGE_OFF + DEGE_BYTES;
constexpr size_t ELIST_OFF = VLIST_OFF + VLIST_BYTES;
constexpr size_t BH_OFF    = ELIST_OFF + ELIST_BYTES;
constexpr size_t BL_OFF    = BH_OFF + BPACK_BYTES;
// total ~48 MB of ws

typedef float    floatx4 __attribute__((ext_vector_type(4)));
typedef short    shortx8 __attribute__((ext_vector_type(8)));
typedef _Float16 halfx4  __attribute__((ext_vector_type(4)));

// RTNE float -> bf16 bits (inputs are well-behaved normals; NaN path not needed)
static __device__ __forceinline__ unsigned short f2bf(float x) {
    unsigned int u = __float_as_uint(x);
    u = u + 0x7fffu + ((u >> 16) & 1u);
    return (unsigned short)(u >> 16);
}
static __device__ __forceinline__ float bf2f(unsigned short h) {
    return __uint_as_float(((unsigned int)h) << 16);
}

// ---------------------------------------------------------------------------
// Pack W (fp32 [K][D] row-major) into MFMA B-fragment layout, split hi/lo bf16.
// Fragment (k0, nt, lane) holds 8 bf16: W[k0*32 + (lane>>4)*8 + j][nt*16 + (lane&15)]
// ---------------------------------------------------------------------------
__global__ __launch_bounds__(256) void pack_w(
        const float* __restrict__ W,
        unsigned short* __restrict__ Bh, unsigned short* __restrict__ Bl) {
    const int idx  = blockIdx.x * 256 + threadIdx.x;  // 0..8191
    const int k0   = idx >> 10;          // 0..7
    const int nt   = (idx >> 6) & 15;    // 0..15
    const int lane = idx & 63;
    const int krow = k0 * 32 + ((lane >> 4) << 3);
    const int ncol = nt * 16 + (lane & 15);
#pragma unroll
    for (int j = 0; j < 8; ++j) {
        const float w = W[(size_t)(krow + j) * DD + ncol];
        const unsigned short h = f2bf(w);
        Bh[(size_t)idx * 8 + j] = h;
        Bl[(size_t)idx * 8 + j] = f2bf(w - bf2f(h));
    }
}

// ---------------------------------------------------------------------------
// GEMM via split-bf16 MFMA, TLP-first (round-5 structure), fp16 output.
// block = 256 thr = 2x2 waves, tile 64 rows x 128 cols; wave = 32x64,
// acc[2][4] = 32 VGPR, no LDS; grid (782,2) = 6256 waves.
// hi*hi + hi*lo + lo*hi (lo*lo dropped) -> ~1e-4 err, then fp16 store (~2^-11).
// ---------------------------------------------------------------------------
__global__ __launch_bounds__(256) void gemm_mfma(
        const float* __restrict__ X,
        const unsigned short* __restrict__ Bh, const unsigned short* __restrict__ Bl,
        _Float16* __restrict__ Xp_h) {
    const int lane = threadIdx.x & 63;
    const int wv   = threadIdx.x >> 6;                 // 0..3
    const int row_base = blockIdx.x * 64 + (wv >> 1) * 32;
    const int ntg0     = blockIdx.y * 8 + (wv & 1) * 4;  // global n-tile base

    floatx4 acc[2][4];
#pragma unroll
    for (int mt = 0; mt < 2; ++mt)
#pragma unroll
        for (int nt = 0; nt < 4; ++nt) acc[mt][nt] = (floatx4)0.f;

    const int lrow   = lane & 15;
    const int kgroup = (lane >> 4) << 3;

    int r0 = row_base + lrow;       if (r0 >= NV) r0 = NV - 1;  // clamp; stores guarded
    int r1 = row_base + 16 + lrow;  if (r1 >= NV) r1 = NV - 1;
    const float* pA0 = &X[(size_t)r0 * KD + kgroup];
    const float* pA1 = &X[(size_t)r1 * KD + kgroup];

    for (int k0 = 0; k0 < 8; ++k0) {
        shortx8 bh[4], bl[4];
#pragma unroll
        for (int nt = 0; nt < 4; ++nt) {
            const size_t boff = ((size_t)(k0 * 16 + ntg0 + nt) * 64 + lane) * 8;
            bh[nt] = *reinterpret_cast<const shortx8*>(&Bh[boff]);
            bl[nt] = *reinterpret_cast<const shortx8*>(&Bl[boff]);
        }
        float xv[2][8];
        *reinterpret_cast<float4*>(&xv[0][0]) = *reinterpret_cast<const float4*>(pA0 + k0 * 32);
        *reinterpret_cast<float4*>(&xv[0][4]) = *reinterpret_cast<const float4*>(pA0 + k0 * 32 + 4);
        *reinterpret_cast<float4*>(&xv[1][0]) = *reinterpret_cast<const float4*>(pA1 + k0 * 32);
        *reinterpret_cast<float4*>(&xv[1][4]) = *reinterpret_cast<const float4*>(pA1 + k0 * 32 + 4);
        shortx8 ah[2], al[2];
#pragma unroll
        for (int mt = 0; mt < 2; ++mt)
#pragma unroll
            for (int j = 0; j < 8; ++j) {
                const unsigned short h = f2bf(xv[mt][j]);
                ah[mt][j] = (short)h;
                al[mt][j] = (short)f2bf(xv[mt][j] - bf2f(h));
            }
#pragma unroll
        for (int nt = 0; nt < 4; ++nt)
#pragma unroll
            for (int mt = 0; mt < 2; ++mt) {
                acc[mt][nt] = __builtin_amdgcn_mfma_f32_16x16x32_bf16(ah[mt], bh[nt], acc[mt][nt], 0, 0, 0);
                acc[mt][nt] = __builtin_amdgcn_mfma_f32_16x16x32_bf16(ah[mt], bl[nt], acc[mt][nt], 0, 0, 0);
                acc[mt][nt] = __builtin_amdgcn_mfma_f32_16x16x32_bf16(al[mt], bh[nt], acc[mt][nt], 0, 0, 0);
            }
    }

    // D fragment: col = lane&15, row = (lane>>4)*4 + reg   [m89-verified]
    const int rgroup = (lane >> 4) << 2;
#pragma unroll
    for (int mt = 0; mt < 2; ++mt) {
#pragma unroll
        for (int r = 0; r < 4; ++r) {
            const int row = row_base + mt * 16 + rgroup + r;
            if (row < NV) {
#pragma unroll
                for (int nt = 0; nt < 4; ++nt)
                    Xp_h[(size_t)row * DD + (ntg0 + nt) * 16 + (lane & 15)] =
                        (_Float16)acc[mt][nt][r];
            }
        }
    }
}

// ---------------------------------------------------------------------------
// Build capacity-padded CSR for both directions in one pass (int atomics only).
// ---------------------------------------------------------------------------
__global__ __launch_bounds__(256) void build_csr(
        const int* __restrict__ vertex, const int* __restrict__ edges,
        int* __restrict__ deg_v, int* __restrict__ deg_e,
        int* __restrict__ vlist, int* __restrict__ elist) {
    const int i = blockIdx.x * blockDim.x + threadIdx.x;
    if (i >= NNZI) return;
    const int v = vertex[i];
    const int e = edges[i];
    const int pe = atomicAdd(&deg_e[e], 1);
    if (pe < ECAP) elist[(size_t)e * ECAP + pe] = v;
    const int pv = atomicAdd(&deg_v[v], 1);
    if (pv < VCAP) vlist[(size_t)v * VCAP + pv] = e;
}

// ---------------------------------------------------------------------------
// Edge aggregation: Xe_h[e,:] = fp16( sum over incidences of fp32(Xp_h[v,:]) )
// One wave per edge; lane owns 4 fp16 (8 B) of the 512 B row.
// x4 unroll: 4 independent row loads in flight.
// ---------------------------------------------------------------------------
__global__ __launch_bounds__(256) void edge_gather(
        const _Float16* __restrict__ Xp_h, const int* __restrict__ deg_e,
        const int* __restrict__ elist, _Float16* __restrict__ Xe_h) {
    const int lane = threadIdx.x & 63;
    const int wid  = (blockIdx.x * blockDim.x + threadIdx.x) >> 6;
    if (wid >= NE) return;
    int cnt = deg_e[wid];
    if (cnt > ECAP) cnt = ECAP;
    const int idxl = elist[(size_t)wid * ECAP + lane];
    const int col  = lane * 4;
    float a0 = 0.f, a1 = 0.f, a2 = 0.f, a3 = 0.f;
    int j = 0;
    for (; j + 4 <= cnt; j += 4) {
        const int v0 = __shfl(idxl, j + 0);
        const int v1 = __shfl(idxl, j + 1);
        const int v2 = __shfl(idxl, j + 2);
        const int v3 = __shfl(idxl, j + 3);
        const halfx4 x0 = *reinterpret_cast<const halfx4*>(&Xp_h[(size_t)v0 * DD + col]);
        const halfx4 x1 = *reinterpret_cast<const halfx4*>(&Xp_h[(size_t)v1 * DD + col]);
        const halfx4 x2 = *reinterpret_cast<const halfx4*>(&Xp_h[(size_t)v2 * DD + col]);
        const halfx4 x3 = *reinterpret_cast<const halfx4*>(&Xp_h[(size_t)v3 * DD + col]);
        a0 += (float)x0[0] + (float)x1[0] + (float)x2[0] + (float)x3[0];
        a1 += (float)x0[1] + (float)x1[1] + (float)x2[1] + (float)x3[1];
        a2 += (float)x0[2] + (float)x1[2] + (float)x2[2] + (float)x3[2];
        a3 += (float)x0[3] + (float)x1[3] + (float)x2[3] + (float)x3[3];
    }
    for (; j < cnt; ++j) {
        const int v = __shfl(idxl, j);
        const halfx4 x = *reinterpret_cast<const halfx4*>(&Xp_h[(size_t)v * DD + col]);
        a0 += (float)x[0]; a1 += (float)x[1]; a2 += (float)x[2]; a3 += (float)x[3];
    }
    halfx4 o;
    o[0] = (_Float16)a0; o[1] = (_Float16)a1; o[2] = (_Float16)a2; o[3] = (_Float16)a3;
    *reinterpret_cast<halfx4*>(&Xe_h[(size_t)wid * DD + col]) = o;
}

// ---------------------------------------------------------------------------
// Vertex aggregation + GIN update: out[v,:] = (1+eps)*Xp[v,:] + sum Xe[e,:]
// fp16 operands, fp32 accumulate + fp32 output.
// ---------------------------------------------------------------------------
__global__ __launch_bounds__(256) void vertex_gather(
        const _Float16* __restrict__ Xp_h, const _Float16* __restrict__ Xe_h,
        const int* __restrict__ deg_v, const int* __restrict__ vlist,
        const float* __restrict__ eps, float* __restrict__ out) {
    const int lane = threadIdx.x & 63;
    const int wid  = (blockIdx.x * blockDim.x + threadIdx.x) >> 6;
    if (wid >= NV) return;
    int cnt = deg_v[wid];
    if (cnt > VCAP) cnt = VCAP;
    // lanes 32..63 read past this row -- harmless: never selected by __shfl (cnt <= 32)
    const int idxl = vlist[(size_t)wid * VCAP + lane];
    const int col  = lane * 4;
    const float e1 = 1.0f + eps[0];
    const halfx4 xp = *reinterpret_cast<const halfx4*>(&Xp_h[(size_t)wid * DD + col]);
    float a0 = e1 * (float)xp[0], a1 = e1 * (float)xp[1];
    float a2 = e1 * (float)xp[2], a3 = e1 * (float)xp[3];
    int j = 0;
    for (; j + 4 <= cnt; j += 4) {
        const int e0 = __shfl(idxl, j + 0);
        const int e1i = __shfl(idxl, j + 1);
        const int e2 = __shfl(idxl, j + 2);
        const int e3 = __shfl(idxl, j + 3);
        const halfx4 t0 = *reinterpret_cast<const halfx4*>(&Xe_h[(size_t)e0 * DD + col]);
        const halfx4 t1 = *reinterpret_cast<const halfx4*>(&Xe_h[(size_t)e1i * DD + col]);
        const halfx4 t2 = *reinterpret_cast<const halfx4*>(&Xe_h[(size_t)e2 * DD + col]);
        const halfx4 t3 = *reinterpret_cast<const halfx4*>(&Xe_h[(size_t)e3 * DD + col]);
        a0 += (float)t0[0] + (float)t1[0] + (float)t2[0] + (float)t3[0];
        a1 += (float)t0[1] + (float)t1[1] + (float)t2[1] + (float)t3[1];
        a2 += (float)t0[2] + (float)t1[2] + (float)t2[2] + (float)t3[2];
        a3 += (float)t0[3] + (float)t1[3] + (float)t2[3] + (float)t3[3];
    }
    for (; j < cnt; ++j) {
        const int e = __shfl(idxl, j);
        const halfx4 t = *reinterpret_cast<const halfx4*>(&Xe_h[(size_t)e * DD + col]);
        a0 += (float)t[0]; a1 += (float)t[1]; a2 += (float)t[2]; a3 += (float)t[3];
    }
    float4 o; o.x = a0; o.y = a1; o.z = a2; o.w = a3;
    *reinterpret_cast<float4*>(&out[(size_t)wid * DD + col]) = o;
}

// ---------------------------------------------------------------------------
extern "C" void kernel_launch(void* const* d_in, const int* in_sizes, int n_in,
                              void* d_out, int out_size, void* d_ws, size_t ws_size,
                              hipStream_t stream) {
    const float* X      = (const float*)d_in[0];
    const int*   vertex = (const int*)d_in[1];
    const int*   edges  = (const int*)d_in[2];
    const float* W      = (const float*)d_in[3];
    const float* eps    = (const float*)d_in[4];
    float* out = (float*)d_out;
    char*  ws  = (char*)d_ws;

    _Float16* Xp_h = (_Float16*)(ws + XPH_OFF);
    _Float16* Xe_h = (_Float16*)(ws + XEH_OFF);
    int*   deg_v = (int*)(ws + DEGV_OFF);
    int*   deg_e = (int*)(ws + DEGE_OFF);
    int*   vlist = (int*)(ws + VLIST_OFF);
    int*   elist = (int*)(ws + ELIST_OFF);
    unsigned short* Bh = (unsigned short*)(ws + BH_OFF);
    unsigned short* Bl = (unsigned short*)(ws + BL_OFF);

    // ws is re-poisoned 0xAA before every timed call: zero the degree counters.
    hipMemsetAsync(ws + DEGV_OFF, 0, DEGV_BYTES + DEGE_BYTES, stream);

    pack_w<<<32, 256, 0, stream>>>(W, Bh, Bl);
    gemm_mfma<<<dim3((NV + 63) / 64, 2), 256, 0, stream>>>(X, Bh, Bl, Xp_h);
    build_csr<<<(NNZI + 255) / 256, 256, 0, stream>>>(vertex, edges, deg_v, deg_e, vlist, elist);
    edge_gather<<<(NE + 3) / 4, 256, 0, stream>>>(Xp_h, deg_e, elist, Xe_h);
    vertex_gather<<<(NV + 3) / 4, 256, 0, stream>>>(Xp_h, Xe_h, deg_v, vlist, eps, out);
}

// Round 8
// 217.319 us; speedup vs baseline: 1.2808x; 1.0465x over previous
//
#include <hip/hip_runtime.h>

// Problem constants (fixed by the reference setup)
constexpr int NV   = 50000;    // num vertices
constexpr int NE   = 20000;    // num hyperedges
constexpr int NNZI = 320000;   // num incidences
constexpr int KD   = 256;      // input feature dim
constexpr int DD   = 256;      // projected feature dim (heads*out)
constexpr int ECAP = 64;       // per-edge incidence capacity (Poisson(16): P(>64) ~ 1e-20)
constexpr int VCAP = 32;       // per-vertex incidence capacity (Poisson(6.4): P(>32) ~ 1e-15)

constexpr size_t alignup256(size_t x) { return (x + 255) & ~(size_t)255; }

constexpr size_t XPH_BYTES   = (size_t)NV * DD * 2;               // 25.6 MB fp16
constexpr size_t XEH_BYTES   = (size_t)NE * DD * 2;               // 10.2 MB fp16
constexpr size_t DEGV_BYTES  = alignup256((size_t)NV * sizeof(int));
constexpr size_t DEGE_BYTES  = alignup256((size_t)NE * sizeof(int));
constexpr size_t VLIST_BYTES = (size_t)NV * VCAP * sizeof(int);   // 6.4 MB
constexpr size_t ELIST_BYTES = (size_t)NE * ECAP * sizeof(int);   // 5.1 MB
// packed W fragments (f16): 8 ksteps x 16 ntiles x 64 lanes x 8 f16 = 128 KB
constexpr size_t BPACK_ELEMS = 8ull * 16 * 64 * 8;
constexpr size_t BPACK_BYTES = BPACK_ELEMS * 2;

constexpr size_t XPH_OFF   = 0;
constexpr size_t XEH_OFF   = XPH_OFF + XPH_BYTES;
constexpr size_t DEGV_OFF  = XEH_OFF + XEH_BYTES;
constexpr size_t DEGE_OFF  = DEGV_OFF + DEGV_BYTES;
constexpr size_t VLIST_OFF = DEGE_OFF + DEGE_BYTES;
constexpr size_t ELIST_OFF = VLIST_OFF + VLIST_BYTES;
constexpr size_t BF_OFF    = ELIST_OFF + ELIST_BYTES;
// total ~48 MB of ws

typedef float    floatx4 __attribute__((ext_vector_type(4)));
typedef _Float16 halfx8  __attribute__((ext_vector_type(8)));
typedef _Float16 halfx4  __attribute__((ext_vector_type(4)));

// ---------------------------------------------------------------------------
// Pack W (fp32 [K][D] row-major) into f16 MFMA B-fragment layout.
// Fragment (k0, nt, lane) holds 8 f16: W[k0*32 + (lane>>4)*8 + j][nt*16 + (lane&15)]
// ---------------------------------------------------------------------------
__global__ __launch_bounds__(256) void pack_w(
        const float* __restrict__ W, _Float16* __restrict__ Bf) {
    const int idx  = blockIdx.x * 256 + threadIdx.x;  // 0..8191
    const int k0   = idx >> 10;          // 0..7
    const int nt   = (idx >> 6) & 15;    // 0..15
    const int lane = idx & 63;
    const int krow = k0 * 32 + ((lane >> 4) << 3);
    const int ncol = nt * 16 + (lane & 15);
#pragma unroll
    for (int j = 0; j < 8; ++j)
        Bf[(size_t)idx * 8 + j] = (_Float16)W[(size_t)(krow + j) * DD + ncol];
}

// ---------------------------------------------------------------------------
// GEMM via single-f16 MFMA (round-7 post-mortem: the split-bf16 path spent
// ~10 VALU/elem in a serial load->convert->MFMA chain; VALUBusy:MfmaUtil 2:1.
// f16 error ~1e-3 at Xp, ~1e-2 after aggregation -- negligible vs the 0.5
// absmax already accepted). Per k0: 4 A-loads (float4) + 4 B-loads (16B)
// + 16 v_cvt_f16_f32 + 8 MFMA, register double-buffered (next k0's loads
// issued before current MFMA block).
// block = 256 thr = 2x2 waves, tile 64 rows x 128 cols; wave = 32x64,
// acc[2][4] = 32 VGPR; grid (782,2) = 6256 waves.
// ---------------------------------------------------------------------------
__global__ __launch_bounds__(256) void gemm_mfma(
        const float* __restrict__ X, const _Float16* __restrict__ Bf,
        _Float16* __restrict__ Xp_h) {
    const int lane = threadIdx.x & 63;
    const int wv   = threadIdx.x >> 6;                 // 0..3
    const int row_base = blockIdx.x * 64 + (wv >> 1) * 32;
    const int ntg0     = blockIdx.y * 8 + (wv & 1) * 4;  // global n-tile base

    floatx4 acc[2][4];
#pragma unroll
    for (int mt = 0; mt < 2; ++mt)
#pragma unroll
        for (int nt = 0; nt < 4; ++nt) acc[mt][nt] = (floatx4)0.f;

    const int lrow   = lane & 15;
    const int kgroup = (lane >> 4) << 3;

    int r0 = row_base + lrow;       if (r0 >= NV) r0 = NV - 1;  // clamp; stores guarded
    int r1 = row_base + 16 + lrow;  if (r1 >= NV) r1 = NV - 1;
    const float* pA0 = &X[(size_t)r0 * KD + kgroup];
    const float* pA1 = &X[(size_t)r1 * KD + kgroup];

    float4 xb[2][2][2];   // [buf][mt][half]
    halfx8 bb[2][4];      // [buf][nt]

    auto loads = [&](int k0, int buf) {
        xb[buf][0][0] = *reinterpret_cast<const float4*>(pA0 + k0 * 32);
        xb[buf][0][1] = *reinterpret_cast<const float4*>(pA0 + k0 * 32 + 4);
        xb[buf][1][0] = *reinterpret_cast<const float4*>(pA1 + k0 * 32);
        xb[buf][1][1] = *reinterpret_cast<const float4*>(pA1 + k0 * 32 + 4);
#pragma unroll
        for (int nt = 0; nt < 4; ++nt) {
            const size_t boff = ((size_t)(k0 * 16 + ntg0 + nt) * 64 + lane) * 8;
            bb[buf][nt] = *reinterpret_cast<const halfx8*>(&Bf[boff]);
        }
    };

    loads(0, 0);
    for (int k0 = 0; k0 < 8; ++k0) {
        const int cur = k0 & 1;
        if (k0 < 7) loads(k0 + 1, cur ^ 1);   // next tile's loads in flight during MFMA
        halfx8 a[2];
#pragma unroll
        for (int mt = 0; mt < 2; ++mt) {
            const float* xp = reinterpret_cast<const float*>(&xb[cur][mt][0]);
#pragma unroll
            for (int j = 0; j < 8; ++j) a[mt][j] = (_Float16)xp[j];
        }
#pragma unroll
        for (int nt = 0; nt < 4; ++nt)
#pragma unroll
            for (int mt = 0; mt < 2; ++mt)
                acc[mt][nt] = __builtin_amdgcn_mfma_f32_16x16x32_f16(a[mt], bb[cur][nt], acc[mt][nt], 0, 0, 0);
    }

    // D fragment: col = lane&15, row = (lane>>4)*4 + reg   [m89-verified]
    const int rgroup = (lane >> 4) << 2;
#pragma unroll
    for (int mt = 0; mt < 2; ++mt) {
#pragma unroll
        for (int r = 0; r < 4; ++r) {
            const int row = row_base + mt * 16 + rgroup + r;
            if (row < NV) {
#pragma unroll
                for (int nt = 0; nt < 4; ++nt)
                    Xp_h[(size_t)row * DD + (ntg0 + nt) * 16 + (lane & 15)] =
                        (_Float16)acc[mt][nt][r];
            }
        }
    }
}

// ---------------------------------------------------------------------------
// Build capacity-padded CSR for both directions in one pass (int atomics only).
// ---------------------------------------------------------------------------
__global__ __launch_bounds__(256) void build_csr(
        const int* __restrict__ vertex, const int* __restrict__ edges,
        int* __restrict__ deg_v, int* __restrict__ deg_e,
        int* __restrict__ vlist, int* __restrict__ elist) {
    const int i = blockIdx.x * blockDim.x + threadIdx.x;
    if (i >= NNZI) return;
    const int v = vertex[i];
    const int e = edges[i];
    const int pe = atomicAdd(&deg_e[e], 1);
    if (pe < ECAP) elist[(size_t)e * ECAP + pe] = v;
    const int pv = atomicAdd(&deg_v[v], 1);
    if (pv < VCAP) vlist[(size_t)v * VCAP + pv] = e;
}

// ---------------------------------------------------------------------------
// Edge aggregation: Xe_h[e,:] = fp16( sum of fp32(Xp_h[v,:]) )
// One wave per edge; lane owns 4 fp16 (8 B). Masked 8-wide chunks: cnt is
// wave-uniform, so sel/scale are uniform (no divergence) and all 8 row loads
// of a chunk are independent and in flight together.
// ---------------------------------------------------------------------------
__global__ __launch_bounds__(256) void edge_gather(
        const _Float16* __restrict__ Xp_h, const int* __restrict__ deg_e,
        const int* __restrict__ elist, _Float16* __restrict__ Xe_h) {
    const int lane = threadIdx.x & 63;
    const int wid  = (blockIdx.x * blockDim.x + threadIdx.x) >> 6;
    if (wid >= NE) return;
    int cnt = deg_e[wid];
    if (cnt > ECAP) cnt = ECAP;
    const int idxl = elist[(size_t)wid * ECAP + lane];
    const int col  = lane * 4;
    float a0 = 0.f, a1 = 0.f, a2 = 0.f, a3 = 0.f;
    for (int base = 0; base < cnt; base += 8) {
#pragma unroll
        for (int jj = 0; jj < 8; ++jj) {
            const int j   = base + jj;
            const int sel = j < cnt ? j : 0;       // wave-uniform
            const float s = j < cnt ? 1.f : 0.f;   // wave-uniform
            const int v = __shfl(idxl, sel);
            const halfx4 x = *reinterpret_cast<const halfx4*>(&Xp_h[(size_t)v * DD + col]);
            a0 = fmaf(s, (float)x[0], a0);
            a1 = fmaf(s, (float)x[1], a1);
            a2 = fmaf(s, (float)x[2], a2);
            a3 = fmaf(s, (float)x[3], a3);
        }
    }
    halfx4 o;
    o[0] = (_Float16)a0; o[1] = (_Float16)a1; o[2] = (_Float16)a2; o[3] = (_Float16)a3;
    *reinterpret_cast<halfx4*>(&Xe_h[(size_t)wid * DD + col]) = o;
}

// ---------------------------------------------------------------------------
// Vertex aggregation + GIN update: out[v,:] = (1+eps)*Xp[v,:] + sum Xe[e,:]
// fp16 operands, fp32 accumulate + fp32 output. Masked 8-wide chunks.
// ---------------------------------------------------------------------------
__global__ __launch_bounds__(256) void vertex_gather(
        const _Float16* __restrict__ Xp_h, const _Float16* __restrict__ Xe_h,
        const int* __restrict__ deg_v, const int* __restrict__ vlist,
        const float* __restrict__ eps, float* __restrict__ out) {
    const int lane = threadIdx.x & 63;
    const int wid  = (blockIdx.x * blockDim.x + threadIdx.x) >> 6;
    if (wid >= NV) return;
    int cnt = deg_v[wid];
    if (cnt > VCAP) cnt = VCAP;
    // lanes 32..63 read past this row -- harmless: sel is always < cnt <= 32
    const int idxl = vlist[(size_t)wid * VCAP + lane];
    const int col  = lane * 4;
    const float e1 = 1.0f + eps[0];
    const halfx4 xp = *reinterpret_cast<const halfx4*>(&Xp_h[(size_t)wid * DD + col]);
    float a0 = e1 * (float)xp[0], a1 = e1 * (float)xp[1];
    float a2 = e1 * (float)xp[2], a3 = e1 * (float)xp[3];
    for (int base = 0; base < cnt; base += 8) {
#pragma unroll
        for (int jj = 0; jj < 8; ++jj) {
            const int j   = base + jj;
            const int sel = j < cnt ? j : 0;       // wave-uniform
            const float s = j < cnt ? 1.f : 0.f;   // wave-uniform
            const int e = __shfl(idxl, sel);
            const halfx4 t = *reinterpret_cast<const halfx4*>(&Xe_h[(size_t)e * DD + col]);
            a0 = fmaf(s, (float)t[0], a0);
            a1 = fmaf(s, (float)t[1], a1);
            a2 = fmaf(s, (float)t[2], a2);
            a3 = fmaf(s, (float)t[3], a3);
        }
    }
    float4 o; o.x = a0; o.y = a1; o.z = a2; o.w = a3;
    *reinterpret_cast<float4*>(&out[(size_t)wid * DD + col]) = o;
}

// ---------------------------------------------------------------------------
extern "C" void kernel_launch(void* const* d_in, const int* in_sizes, int n_in,
                              void* d_out, int out_size, void* d_ws, size_t ws_size,
                              hipStream_t stream) {
    const float* X      = (const float*)d_in[0];
    const int*   vertex = (const int*)d_in[1];
    const int*   edges  = (const int*)d_in[2];
    const float* W      = (const float*)d_in[3];
    const float* eps    = (const float*)d_in[4];
    float* out = (float*)d_out;
    char*  ws  = (char*)d_ws;

    _Float16* Xp_h = (_Float16*)(ws + XPH_OFF);
    _Float16* Xe_h = (_Float16*)(ws + XEH_OFF);
    int*   deg_v = (int*)(ws + DEGV_OFF);
    int*   deg_e = (int*)(ws + DEGE_OFF);
    int*   vlist = (int*)(ws + VLIST_OFF);
    int*   elist = (int*)(ws + ELIST_OFF);
    _Float16* Bf  = (_Float16*)(ws + BF_OFF);

    // ws is re-poisoned 0xAA before every timed call: zero the degree counters.
    hipMemsetAsync(ws + DEGV_OFF, 0, DEGV_BYTES + DEGE_BYTES, stream);

    pack_w<<<32, 256, 0, stream>>>(W, Bf);
    gemm_mfma<<<dim3((NV + 63) / 64, 2), 256, 0, stream>>>(X, Bf, Xp_h);
    build_csr<<<(NNZI + 255) / 256, 256, 0, stream>>>(vertex, edges, deg_v, deg_e, vlist, elist);
    edge_gather<<<(NE + 3) / 4, 256, 0, stream>>>(Xp_h, deg_e, elist, Xe_h);
    vertex_gather<<<(NV + 3) / 4, 256, 0, stream>>>(Xp_h, Xe_h, deg_v, vlist, eps, out);
}

// Round 9
// 215.516 us; speedup vs baseline: 1.2915x; 1.0084x over previous
//
#include <hip/hip_runtime.h>

// Problem constants (fixed by the reference setup)
constexpr int NV   = 50000;    // num vertices
constexpr int NE   = 20000;    // num hyperedges
constexpr int NNZI = 320000;   // num incidences
constexpr int KD   = 256;      // input feature dim
constexpr int DD   = 256;      // projected feature dim (heads*out)
constexpr int ECAP = 64;       // per-edge incidence capacity (Poisson(16): P(>64) ~ 1e-20)
constexpr int VCAP = 32;       // per-vertex incidence capacity (Poisson(6.4): P(>32) ~ 1e-15)

constexpr size_t alignup256(size_t x) { return (x + 255) & ~(size_t)255; }

constexpr size_t XPH_BYTES   = (size_t)NV * DD * 2;               // 25.6 MB fp16
constexpr size_t XEH_BYTES   = (size_t)NE * DD * 2;               // 10.2 MB fp16
constexpr size_t XH_BYTES    = (size_t)NV * KD * 2;               // 25.6 MB fp16 (cast of X)
constexpr size_t DEGV_BYTES  = alignup256((size_t)NV * sizeof(int));
constexpr size_t DEGE_BYTES  = alignup256((size_t)NE * sizeof(int));
constexpr size_t VLIST_BYTES = (size_t)NV * VCAP * sizeof(int);   // 6.4 MB
constexpr size_t ELIST_BYTES = (size_t)NE * ECAP * sizeof(int);   // 5.1 MB
// packed W fragments (f16): 8 ksteps x 16 ntiles x 64 lanes x 8 f16 = 128 KB
constexpr size_t BPACK_ELEMS = 8ull * 16 * 64 * 8;
constexpr size_t BPACK_BYTES = BPACK_ELEMS * 2;

constexpr size_t XPH_OFF   = 0;
constexpr size_t XEH_OFF   = XPH_OFF + XPH_BYTES;
constexpr size_t XH_OFF    = XEH_OFF + XEH_BYTES;
constexpr size_t DEGV_OFF  = XH_OFF + XH_BYTES;
constexpr size_t DEGE_OFF  = DEGV_OFF + DEGV_BYTES;
constexpr size_t VLIST_OFF = DEGE_OFF + DEGE_BYTES;
constexpr size_t ELIST_OFF = VLIST_OFF + VLIST_BYTES;
constexpr size_t BF_OFF    = ELIST_OFF + ELIST_BYTES;
// total ~74 MB of ws

typedef float    floatx4 __attribute__((ext_vector_type(4)));
typedef _Float16 halfx8  __attribute__((ext_vector_type(8)));
typedef _Float16 halfx4  __attribute__((ext_vector_type(4)));

// fused_prep block-range split
constexpr int CAST_BLOCKS = 1024;
constexpr int PACK_BLOCKS = 32;
constexpr int CSR_BLOCKS  = (NNZI + 255) / 256;   // 1250
constexpr int PREP_BLOCKS = CAST_BLOCKS + PACK_BLOCKS + CSR_BLOCKS;

// ---------------------------------------------------------------------------
// Fused prep: three independent roles split by block range (they currently
// serialize as 3 kernels; fused, the BW-bound cast overlaps the atomic/
// latency-bound CSR build).
//  role A (1024 blocks): X fp32 -> fp16 cast (RTNE; bit-identical to the
//    in-register convert the round-8 gemm did, so no new error).
//  role B (32 blocks): pack W into f16 MFMA B-fragment layout:
//    fragment (k0,nt,lane) = W[k0*32+(lane>>4)*8+j][nt*16+(lane&15)]
//  role C (1250 blocks): capacity-padded CSR build (int atomics only).
// ---------------------------------------------------------------------------
__global__ __launch_bounds__(256) void fused_prep(
        const float* __restrict__ X, const float* __restrict__ W,
        const int* __restrict__ vertex, const int* __restrict__ edges,
        _Float16* __restrict__ X_h, _Float16* __restrict__ Bf,
        int* __restrict__ deg_v, int* __restrict__ deg_e,
        int* __restrict__ vlist, int* __restrict__ elist) {
    const int b = blockIdx.x;
    if (b < CAST_BLOCKS) {
        constexpr int NCHUNK = NV * KD / 8;   // 1.6M chunks of 8 floats
        const int tid = b * 256 + threadIdx.x;
        for (int c = tid; c < NCHUNK; c += CAST_BLOCKS * 256) {
            const float4 lo = *reinterpret_cast<const float4*>(&X[(size_t)c * 8]);
            const float4 hi = *reinterpret_cast<const float4*>(&X[(size_t)c * 8 + 4]);
            halfx8 h;
            h[0] = (_Float16)lo.x; h[1] = (_Float16)lo.y;
            h[2] = (_Float16)lo.z; h[3] = (_Float16)lo.w;
            h[4] = (_Float16)hi.x; h[5] = (_Float16)hi.y;
            h[6] = (_Float16)hi.z; h[7] = (_Float16)hi.w;
            *reinterpret_cast<halfx8*>(&X_h[(size_t)c * 8]) = h;
        }
    } else if (b < CAST_BLOCKS + PACK_BLOCKS) {
        const int idx  = (b - CAST_BLOCKS) * 256 + threadIdx.x;  // 0..8191
        const int k0   = idx >> 10;
        const int nt   = (idx >> 6) & 15;
        const int lane = idx & 63;
        const int krow = k0 * 32 + ((lane >> 4) << 3);
        const int ncol = nt * 16 + (lane & 15);
#pragma unroll
        for (int j = 0; j < 8; ++j)
            Bf[(size_t)idx * 8 + j] = (_Float16)W[(size_t)(krow + j) * DD + ncol];
    } else {
        const int i = (b - CAST_BLOCKS - PACK_BLOCKS) * 256 + threadIdx.x;
        if (i < NNZI) {
            const int v = vertex[i];
            const int e = edges[i];
            const int pe = atomicAdd(&deg_e[e], 1);
            if (pe < ECAP) elist[(size_t)e * ECAP + pe] = v;
            const int pv = atomicAdd(&deg_v[v], 1);
            if (pv < VCAP) vlist[(size_t)v * VCAP + pv] = e;
        }
    }
}

// ---------------------------------------------------------------------------
// GEMM, pure-f16 operands from memory (round-8 post-mortem: the fp32 A-loads
// + 16 v_cvt per k0 formed the serial chain; A is now pre-cast, so per k0 =
// 2 A-loads (b128) + 4 B-loads (b128) + 8 MFMA, zero VALU, register
// double-buffered).
// block = 256 thr = 2x2 waves, tile 64 rows x 128 cols; wave = 32x64,
// acc[2][4] = 32 VGPR; grid (782,2) = 6256 waves.
// ---------------------------------------------------------------------------
__global__ __launch_bounds__(256, 4) void gemm_mfma(
        const _Float16* __restrict__ X_h, const _Float16* __restrict__ Bf,
        _Float16* __restrict__ Xp_h) {
    const int lane = threadIdx.x & 63;
    const int wv   = threadIdx.x >> 6;                 // 0..3
    const int row_base = blockIdx.x * 64 + (wv >> 1) * 32;
    const int ntg0     = blockIdx.y * 8 + (wv & 1) * 4;  // global n-tile base

    floatx4 acc[2][4];
#pragma unroll
    for (int mt = 0; mt < 2; ++mt)
#pragma unroll
        for (int nt = 0; nt < 4; ++nt) acc[mt][nt] = (floatx4)0.f;

    const int lrow   = lane & 15;
    const int kgroup = (lane >> 4) << 3;   // k sub-offset in f16 elems (0,8,16,24)

    int r0 = row_base + lrow;       if (r0 >= NV) r0 = NV - 1;  // clamp; stores guarded
    int r1 = row_base + 16 + lrow;  if (r1 >= NV) r1 = NV - 1;
    const _Float16* pA0 = &X_h[(size_t)r0 * KD + kgroup];
    const _Float16* pA1 = &X_h[(size_t)r1 * KD + kgroup];

    halfx8 ab[2][2];   // [buf][mt]
    halfx8 bb[2][4];   // [buf][nt]

    auto loads = [&](int k0, int buf) {
        ab[buf][0] = *reinterpret_cast<const halfx8*>(pA0 + k0 * 32);
        ab[buf][1] = *reinterpret_cast<const halfx8*>(pA1 + k0 * 32);
#pragma unroll
        for (int nt = 0; nt < 4; ++nt) {
            const size_t boff = ((size_t)(k0 * 16 + ntg0 + nt) * 64 + lane) * 8;
            bb[buf][nt] = *reinterpret_cast<const halfx8*>(&Bf[boff]);
        }
    };

    loads(0, 0);
    for (int k0 = 0; k0 < 8; ++k0) {
        const int cur = k0 & 1;
        if (k0 < 7) loads(k0 + 1, cur ^ 1);   // next tile's loads in flight during MFMA
#pragma unroll
        for (int nt = 0; nt < 4; ++nt)
#pragma unroll
            for (int mt = 0; mt < 2; ++mt)
                acc[mt][nt] = __builtin_amdgcn_mfma_f32_16x16x32_f16(
                    ab[cur][mt], bb[cur][nt], acc[mt][nt], 0, 0, 0);
    }

    // D fragment: col = lane&15, row = (lane>>4)*4 + reg   [m89-verified]
    const int rgroup = (lane >> 4) << 2;
#pragma unroll
    for (int mt = 0; mt < 2; ++mt) {
#pragma unroll
        for (int r = 0; r < 4; ++r) {
            const int row = row_base + mt * 16 + rgroup + r;
            if (row < NV) {
#pragma unroll
                for (int nt = 0; nt < 4; ++nt)
                    Xp_h[(size_t)row * DD + (ntg0 + nt) * 16 + (lane & 15)] =
                        (_Float16)acc[mt][nt][r];
            }
        }
    }
}

// ---------------------------------------------------------------------------
// Edge aggregation: Xe_h[e,:] = fp16( sum of fp32(Xp_h[v,:]) )
// One wave per edge; lane owns 4 fp16 (8 B). Masked 8-wide chunks: cnt is
// wave-uniform, so sel/scale are uniform and all 8 row loads are in flight.
// ---------------------------------------------------------------------------
__global__ __launch_bounds__(256) void edge_gather(
        const _Float16* __restrict__ Xp_h, const int* __restrict__ deg_e,
        const int* __restrict__ elist, _Float16* __restrict__ Xe_h) {
    const int lane = threadIdx.x & 63;
    const int wid  = (blockIdx.x * blockDim.x + threadIdx.x) >> 6;
    if (wid >= NE) return;
    int cnt = deg_e[wid];
    if (cnt > ECAP) cnt = ECAP;
    const int idxl = elist[(size_t)wid * ECAP + lane];
    const int col  = lane * 4;
    float a0 = 0.f, a1 = 0.f, a2 = 0.f, a3 = 0.f;
    for (int base = 0; base < cnt; base += 8) {
#pragma unroll
        for (int jj = 0; jj < 8; ++jj) {
            const int j   = base + jj;
            const int sel = j < cnt ? j : 0;       // wave-uniform
            const float s = j < cnt ? 1.f : 0.f;   // wave-uniform
            const int v = __shfl(idxl, sel);
            const halfx4 x = *reinterpret_cast<const halfx4*>(&Xp_h[(size_t)v * DD + col]);
            a0 = fmaf(s, (float)x[0], a0);
            a1 = fmaf(s, (float)x[1], a1);
            a2 = fmaf(s, (float)x[2], a2);
            a3 = fmaf(s, (float)x[3], a3);
        }
    }
    halfx4 o;
    o[0] = (_Float16)a0; o[1] = (_Float16)a1; o[2] = (_Float16)a2; o[3] = (_Float16)a3;
    *reinterpret_cast<halfx4*>(&Xe_h[(size_t)wid * DD + col]) = o;
}

// ---------------------------------------------------------------------------
// Vertex aggregation + GIN update: out[v,:] = (1+eps)*Xp[v,:] + sum Xe[e,:]
// fp16 operands, fp32 accumulate + fp32 output. Masked 8-wide chunks.
// ---------------------------------------------------------------------------
__global__ __launch_bounds__(256) void vertex_gather(
        const _Float16* __restrict__ Xp_h, const _Float16* __restrict__ Xe_h,
        const int* __restrict__ deg_v, const int* __restrict__ vlist,
        const float* __restrict__ eps, float* __restrict__ out) {
    const int lane = threadIdx.x & 63;
    const int wid  = (blockIdx.x * blockDim.x + threadIdx.x) >> 6;
    if (wid >= NV) return;
    int cnt = deg_v[wid];
    if (cnt > VCAP) cnt = VCAP;
    // lanes 32..63 read past this row -- harmless: sel is always < cnt <= 32
    const int idxl = vlist[(size_t)wid * VCAP + lane];
    const int col  = lane * 4;
    const float e1 = 1.0f + eps[0];
    const halfx4 xp = *reinterpret_cast<const halfx4*>(&Xp_h[(size_t)wid * DD + col]);
    float a0 = e1 * (float)xp[0], a1 = e1 * (float)xp[1];
    float a2 = e1 * (float)xp[2], a3 = e1 * (float)xp[3];
    for (int base = 0; base < cnt; base += 8) {
#pragma unroll
        for (int jj = 0; jj < 8; ++jj) {
            const int j   = base + jj;
            const int sel = j < cnt ? j : 0;       // wave-uniform
            const float s = j < cnt ? 1.f : 0.f;   // wave-uniform
            const int e = __shfl(idxl, sel);
            const halfx4 t = *reinterpret_cast<const halfx4*>(&Xe_h[(size_t)e * DD + col]);
            a0 = fmaf(s, (float)t[0], a0);
            a1 = fmaf(s, (float)t[1], a1);
            a2 = fmaf(s, (float)t[2], a2);
            a3 = fmaf(s, (float)t[3], a3);
        }
    }
    float4 o; o.x = a0; o.y = a1; o.z = a2; o.w = a3;
    *reinterpret_cast<float4*>(&out[(size_t)wid * DD + col]) = o;
}

// ---------------------------------------------------------------------------
extern "C" void kernel_launch(void* const* d_in, const int* in_sizes, int n_in,
                              void* d_out, int out_size, void* d_ws, size_t ws_size,
                              hipStream_t stream) {
    const float* X      = (const float*)d_in[0];
    const int*   vertex = (const int*)d_in[1];
    const int*   edges  = (const int*)d_in[2];
    const float* W      = (const float*)d_in[3];
    const float* eps    = (const float*)d_in[4];
    float* out = (float*)d_out;
    char*  ws  = (char*)d_ws;

    _Float16* Xp_h = (_Float16*)(ws + XPH_OFF);
    _Float16* Xe_h = (_Float16*)(ws + XEH_OFF);
    _Float16* X_h  = (_Float16*)(ws + XH_OFF);
    int*   deg_v = (int*)(ws + DEGV_OFF);
    int*   deg_e = (int*)(ws + DEGE_OFF);
    int*   vlist = (int*)(ws + VLIST_OFF);
    int*   elist = (int*)(ws + ELIST_OFF);
    _Float16* Bf  = (_Float16*)(ws + BF_OFF);

    // ws is re-poisoned 0xAA before every timed call: zero the degree counters.
    hipMemsetAsync(ws + DEGV_OFF, 0, DEGV_BYTES + DEGE_BYTES, stream);

    fused_prep<<<PREP_BLOCKS, 256, 0, stream>>>(
        X, W, vertex, edges, X_h, Bf, deg_v, deg_e, vlist, elist);
    gemm_mfma<<<dim3((NV + 63) / 64, 2), 256, 0, stream>>>(X_h, Bf, Xp_h);
    edge_gather<<<(NE + 3) / 4, 256, 0, stream>>>(Xp_h, deg_e, elist, Xe_h);
    vertex_gather<<<(NV + 3) / 4, 256, 0, stream>>>(Xp_h, Xe_h, deg_v, vlist, eps, out);
}